// Round 2
// baseline (298.521 us; speedup 1.0000x reference)
//
#include <hip/hip_runtime.h>
#include <stdint.h>

typedef __bf16 bf16x8 __attribute__((ext_vector_type(8)));
typedef float f32x4 __attribute__((ext_vector_type(4)));
typedef unsigned short u16;

__device__ __forceinline__ u16 f2b(float f) {
  union { float f; uint32_t u; } a; a.f = f;
  return (u16)((a.u + 0x7FFFu + ((a.u >> 16) & 1u)) >> 16);  // RNE
}
__device__ __forceinline__ float b2f(u16 b) {
  union { uint32_t u; float f; } a; a.u = ((uint32_t)b) << 16; return a.f;
}

// ---------------- f32 -> bf16 convert (4 elems/thread) ----------------
__global__ void cvt_kernel(const float* __restrict__ in, u16* __restrict__ out, int n4) {
  int i = blockIdx.x * 256 + threadIdx.x;
  if (i >= n4) return;
  float4 v = reinterpret_cast<const float4*>(in)[i];
  ushort4 o;
  o.x = f2b(v.x); o.y = f2b(v.y); o.z = f2b(v.z); o.w = f2b(v.w);
  reinterpret_cast<ushort4*>(out)[i] = o;
}

// ---------------- bf16 MFMA GEMM: C[m,n] = sum_k A[m,k]*Bt[n,k] ----------------
// A: [M][K] bf16 row-major, Bt: [N][K] bf16 row-major (i.e. B^T layout).
// 128x128 tile, BK=32, 4 waves (2x2), each wave 64x64 via 4x4 frags of 16x16x32.
#define BM 128
#define BN 128
#define BKK 32
#define LDT 40   // padded LDS row stride (elements) -> conflict-free ds_read_b128

template<bool PROJ>
__global__ __launch_bounds__(256) void gemm_bt(
    const u16* __restrict__ A, const u16* __restrict__ Bt,
    u16* __restrict__ Cb, float* __restrict__ Cf, const float* __restrict__ bias,
    int N, int K)
{
  __shared__ __align__(16) u16 As[BM * LDT];
  __shared__ __align__(16) u16 Bs[BN * LDT];
  const int tid = threadIdx.x;
  const int lane = tid & 63;
  const int wid = tid >> 6;
  const int wm = wid >> 1, wn = wid & 1;
  const size_t bm = (size_t)blockIdx.x * BM;
  const size_t bn = (size_t)blockIdx.y * BN;

  f32x4 acc[4][4] = {};
  const int fr = lane & 15;
  const int fk = (lane >> 4) * 8;

  // staging: 512 chunks of 16B per tile; thread handles chunk tid and tid+256
  const int r0 = tid >> 2, c0 = (tid & 3) * 8;
  const int r1 = r0 + 64;

  const u16* Arow0 = A + (bm + r0) * (size_t)K + c0;
  const u16* Arow1 = A + (bm + r1) * (size_t)K + c0;
  const u16* Brow0 = Bt + (bn + r0) * (size_t)K + c0;
  const u16* Brow1 = Bt + (bn + r1) * (size_t)K + c0;

  for (int k0 = 0; k0 < K; k0 += BKK) {
    uint4 a0 = *reinterpret_cast<const uint4*>(Arow0 + k0);
    uint4 a1 = *reinterpret_cast<const uint4*>(Arow1 + k0);
    uint4 b0 = *reinterpret_cast<const uint4*>(Brow0 + k0);
    uint4 b1 = *reinterpret_cast<const uint4*>(Brow1 + k0);
    __syncthreads();   // prev iter's frag reads done before overwrite
    *reinterpret_cast<uint4*>(&As[r0 * LDT + c0]) = a0;
    *reinterpret_cast<uint4*>(&As[r1 * LDT + c0]) = a1;
    *reinterpret_cast<uint4*>(&Bs[r0 * LDT + c0]) = b0;
    *reinterpret_cast<uint4*>(&Bs[r1 * LDT + c0]) = b1;
    __syncthreads();
    bf16x8 af[4], bv[4];
#pragma unroll
    for (int m = 0; m < 4; ++m)
      af[m] = *reinterpret_cast<const bf16x8*>(&As[(wm * 64 + m * 16 + fr) * LDT + fk]);
#pragma unroll
    for (int n = 0; n < 4; ++n)
      bv[n] = *reinterpret_cast<const bf16x8*>(&Bs[(wn * 64 + n * 16 + fr) * LDT + fk]);
#pragma unroll
    for (int m = 0; m < 4; ++m)
#pragma unroll
      for (int n = 0; n < 4; ++n)
        acc[m][n] = __builtin_amdgcn_mfma_f32_16x16x32_bf16(af[m], bv[n], acc[m][n], 0, 0, 0);
  }
  // epilogue: D row=(lane>>4)*4+reg, col=lane&15 (m89-verified layout)
  const int fq = lane >> 4;
#pragma unroll
  for (int m = 0; m < 4; ++m) {
#pragma unroll
    for (int n = 0; n < 4; ++n) {
#pragma unroll
      for (int r = 0; r < 4; ++r) {
        size_t row = bm + wm * 64 + m * 16 + fq * 4 + r;
        size_t col = bn + wn * 64 + n * 16 + fr;
        float v = acc[m][n][r];
        if (PROJ) Cf[row * N + col] = v + bias[col];
        else      Cb[row * N + col] = f2b(v);
      }
    }
  }
}

// ---------------- per-pixel attention, 1 wave per pixel ----------------
// lane = dim d (0..63). Writes the [b][e][n][h] "scramble" layout directly (bf16).
__global__ __launch_bounds__(64) void attn_pixel(
    const u16* __restrict__ Qm, const u16* __restrict__ Km,
    const u16* __restrict__ Vm, u16* __restrict__ Sc)
{
  struct S1 {
    float vh[8][68];   // normalized v rows (padded: bank (4h+i)%32, conflict-free)
    float a8[64];      // head-mix attention A[h][g]
    float q2[64][12];  // q2 transposed [e][h] (48B rows, 16B aligned)
  };
  __shared__ __align__(16) union { S1 s1; float at[64][65]; } sm;  // at overlays s1 (dead by then)
  __shared__ __align__(16) float vvs[64][12];                      // vv transposed [d][h]

  const int bid = blockIdx.x;
  const int pix = (bid & 7) * 2048 + (bid >> 3);   // XCD-chunked swizzle (16384 = 8*2048)
  const int b = pix >> 12;
  const int n = pix & 4095;
  const int lane = threadIdx.x;
  const size_t base = (size_t)pix * 512 + lane;

  float qv[8], kv[8], vv[8];
#pragma unroll
  for (int h = 0; h < 8; ++h) {
    qv[h] = b2f(Qm[base + h * 64]);
    kv[h] = b2f(Km[base + h * 64]);
    vv[h] = 2.0f * b2f(Vm[base + h * 64]);   // reference's v = v + v
  }
  // l2 norms over the 64 lanes (per head)
#pragma unroll
  for (int h = 0; h < 8; ++h) {
    float s = qv[h] * qv[h];
#pragma unroll
    for (int m = 1; m < 64; m <<= 1) s += __shfl_xor(s, m, 64);
    qv[h] *= 1.0f / fmaxf(sqrtf(s), 1e-12f);
  }
#pragma unroll
  for (int h = 0; h < 8; ++h) {
    float s = kv[h] * kv[h];
#pragma unroll
    for (int m = 1; m < 64; m <<= 1) s += __shfl_xor(s, m, 64);
    kv[h] *= 1.0f / fmaxf(sqrtf(s), 1e-12f);
  }
#pragma unroll
  for (int h = 0; h < 8; ++h) {
    float s = vv[h] * vv[h];
#pragma unroll
    for (int m = 1; m < 64; m <<= 1) s += __shfl_xor(s, m, 64);
    sm.s1.vh[h][lane] = vv[h] * (1.0f / fmaxf(sqrtf(s), 1e-12f));
  }
  __syncthreads();

  // 8x8 gram of v_h + row softmax; lane -> (hh,gg)
  const int hh = lane >> 3, gg = lane & 7;
  float g = 0.0f;
#pragma unroll
  for (int i = 0; i < 64; ++i) g += sm.s1.vh[hh][i] * sm.s1.vh[gg][i];
  float mx = g;
  mx = fmaxf(mx, __shfl_xor(mx, 1, 64));
  mx = fmaxf(mx, __shfl_xor(mx, 2, 64));
  mx = fmaxf(mx, __shfl_xor(mx, 4, 64));
  float ex = __expf(g - mx);
  float sum = ex;
  sum += __shfl_xor(sum, 1, 64);
  sum += __shfl_xor(sum, 2, 64);
  sum += __shfl_xor(sum, 4, 64);
  sm.s1.a8[lane] = ex / sum;
  __syncthreads();

  // head-mix q and k: q2[h] = sum_g A[h][g] * q[g]   (broadcast LDS reads)
  float q2[8], k2[8];
#pragma unroll
  for (int h = 0; h < 8; ++h) {
    float aq = 0.0f, ak = 0.0f;
#pragma unroll
    for (int gi = 0; gi < 8; ++gi) {
      float a = sm.s1.a8[h * 8 + gi];
      aq += a * qv[gi]; ak += a * kv[gi];
    }
    q2[h] = aq; k2[h] = ak;
  }
  // stash transposed q2, vv
#pragma unroll
  for (int h = 0; h < 8; ++h) { sm.s1.q2[lane][h] = q2[h]; vvs[lane][h] = vv[h]; }
  __syncthreads();

  // S[d][e] = sum_h k2[h][d]*q2[h][e]; lane owns row d; full row in regs
  float sv[64];
#pragma unroll
  for (int e = 0; e < 64; ++e) {
    float a = 0.0f;
#pragma unroll
    for (int h = 0; h < 8; ++h) a += k2[h] * sm.s1.q2[e][h];
    sv[e] = a;
  }
  // in-lane softmax over e (no cross-lane traffic)
  float m2 = sv[0];
#pragma unroll
  for (int e = 1; e < 64; ++e) m2 = fmaxf(m2, sv[e]);
  float l = 0.0f;
#pragma unroll
  for (int e = 0; e < 64; ++e) { sv[e] = __expf(sv[e] - m2); l += sv[e]; }
  float invl = 1.0f / l;
  __syncthreads();   // all lanes done reading q2 before at[] overlays it

  // transpose attn through LDS: at[d][e], 65-pad -> conflict-free both sides
#pragma unroll
  for (int e = 0; e < 64; ++e) sm.at[lane][e] = sv[e] * invl;
  __syncthreads();

  // PV: lane owns col e; out[h][e] = sum_d vv[h][d]*attn[d][e]
  float out[8] = {0,0,0,0,0,0,0,0};
#pragma unroll
  for (int d = 0; d < 64; ++d) {
    float p = sm.at[d][lane];
#pragma unroll
    for (int h = 0; h < 8; ++h) out[h] += vvs[d][h] * p;
  }

  // scramble store: scr[b][e*64 + n/64][(n%64)*8 + h], e = lane, bf16x8 = 16B
  uint32_t p0 = (uint32_t)f2b(out[0]) | ((uint32_t)f2b(out[1]) << 16);
  uint32_t p1 = (uint32_t)f2b(out[2]) | ((uint32_t)f2b(out[3]) << 16);
  uint32_t p2 = (uint32_t)f2b(out[4]) | ((uint32_t)f2b(out[5]) << 16);
  uint32_t p3 = (uint32_t)f2b(out[6]) | ((uint32_t)f2b(out[7]) << 16);
  uint4 pk; pk.x = p0; pk.y = p1; pk.z = p2; pk.w = p3;
  size_t doff = (size_t)b * 2097152 + ((size_t)lane * 64 + (size_t)(n >> 6)) * 512
              + (size_t)(n & 63) * 8;
  *reinterpret_cast<uint4*>(Sc + doff) = pk;
}

// ---------------- launcher ----------------
extern "C" void kernel_launch(void* const* d_in, const int* in_sizes, int n_in,
                              void* d_out, int out_size, void* d_ws, size_t ws_size,
                              hipStream_t stream) {
  const float* x  = (const float*)d_in[0];
  const float* Wq = (const float*)d_in[1];
  const float* Wk = (const float*)d_in[2];
  const float* Wv = (const float*)d_in[3];
  // d_in[4] = conv_w: dead code in the reference
  const float* Pw = (const float*)d_in[5];
  const float* Pb = (const float*)d_in[6];
  float* out = (float*)d_out;

  const size_t MK = 16384ull * 512ull;     // 8.4M elems
  u16* Xb  = (u16*)d_ws;
  u16* Qb  = Xb + MK;
  u16* Kb  = Qb + MK;
  u16* Vb  = Kb + MK;
  u16* Scr = Vb + MK;
  u16* Wqb = Scr + MK;
  u16* Wkb = Wqb + 512 * 512;
  u16* Wvb = Wkb + 512 * 512;
  u16* Pwb = Wvb + 512 * 512;
  // total ws use: 5*16.78MB + 4*0.5MB ≈ 86 MB

  cvt_kernel<<<8192, 256, 0, stream>>>(x,  Xb,  2097152);
  cvt_kernel<<<256,  256, 0, stream>>>(Wq, Wqb, 65536);
  cvt_kernel<<<256,  256, 0, stream>>>(Wk, Wkb, 65536);
  cvt_kernel<<<256,  256, 0, stream>>>(Wv, Wvb, 65536);
  cvt_kernel<<<256,  256, 0, stream>>>(Pw, Pwb, 65536);

  dim3 gg(128, 4);
  gemm_bt<false><<<gg, 256, 0, stream>>>(Xb, Wqb, Qb, nullptr, nullptr, 512, 512);
  gemm_bt<false><<<gg, 256, 0, stream>>>(Xb, Wkb, Kb, nullptr, nullptr, 512, 512);
  gemm_bt<false><<<gg, 256, 0, stream>>>(Xb, Wvb, Vb, nullptr, nullptr, 512, 512);

  attn_pixel<<<16384, 64, 0, stream>>>(Qb, Kb, Vb, Scr);

  gemm_bt<true><<<gg, 256, 0, stream>>>(Scr, Pwb, nullptr, out, Pb, 512, 512);
}